// Round 5
// baseline (458.508 us; speedup 1.0000x reference)
//
#include <hip/hip_runtime.h>

// Problem constants (fixed by reference): B=4, S=2048, DIN=4096, DOUT=4096
#define GM 8192   // M = B*S
#define GN 4096   // N = DOUT
#define GK 4096   // K = DIN

#define BM 256
#define BN 256
#define BK 64             // bytes of K per K-tile (i8)
#define NTILE (GK / BK)   // 64 K-tiles
#define ASLOT 16384       // one A K-tile (256 rows x 64 B)

using int4v = __attribute__((ext_vector_type(4))) int;

// ---------------- fused quantization ----------------
// x path: x_int8 = (int)(x * input_scale)      -- trunc toward zero
// w path: w_int8 = (int)rintf(w * wscale[row]) -- round half-even
__global__ __launch_bounds__(256) void quant_xw_k(
    const float4* __restrict__ x, unsigned int* __restrict__ xq,
    const float4* __restrict__ w, unsigned int* __restrict__ wq,
    const float* __restrict__ wscale, const float* __restrict__ iscale,
    int n4x, int n4tot) {
    const float xs = *iscale;
    const int stride = gridDim.x * blockDim.x;
    for (int i = blockIdx.x * blockDim.x + threadIdx.x; i < n4tot; i += stride) {
        if (i < n4x) {
            float4 v = x[i];
            int q0 = (int)(v.x * xs);
            int q1 = (int)(v.y * xs);
            int q2 = (int)(v.z * xs);
            int q3 = (int)(v.w * xs);
            xq[i] = (unsigned int)(q0 & 0xff)
                  | ((unsigned int)(q1 & 0xff) << 8)
                  | ((unsigned int)(q2 & 0xff) << 16)
                  | ((unsigned int)(q3 & 0xff) << 24);
        } else {
            int j = i - n4x;
            float s = wscale[j >> 10];
            float4 v = w[j];
            int q0 = (int)rintf(v.x * s);
            int q1 = (int)rintf(v.y * s);
            int q2 = (int)rintf(v.z * s);
            int q3 = (int)rintf(v.w * s);
            wq[j] = (unsigned int)(q0 & 0xff)
                  | ((unsigned int)(q1 & 0xff) << 8)
                  | ((unsigned int)(q2 & 0xff) << 16)
                  | ((unsigned int)(q3 & 0xff) << 24);
        }
    }
}

// ---------------- int8 GEMM: A via LDS, B streamed from global ------------
// 256x256 tile, 512 thr, 8 waves 2Mx4N (wave tile 128x64, acc[8][4]).
// Rationale (R0-R4 post-mortems): LDS pipe time and MFMA time add in every
// schedule; i8 fragment traffic (96r+32w KiB/K-tile) makes LDS the co-equal
// bottleneck. Fix = remove B from LDS: B fragments (lane&15=row, lane>>4 =
// 16B k-chunk) load directly from global as dwordx4 (L2-resident panel,
// dup 2), prefetched one K-tile ahead into registers. LDS now carries only
// A: 16w + 64r KiB per K-tile.
// VMEM issue order per tile t (pinned by sched_barrier(0) fences):
//   [B(t+1) x4][GLL A(t+2) x2] ... wait vmcnt(8)  -> retires B(t)
//   ... after MFMA: wait vmcnt(6)                 -> retires GLL A(t+1)
//   s_barrier. Invariant at loop top: in flight = [B(t) x4, GLL A(t+1) x2].
// 3 A slots: GLL(t+2) overwrites slot(t-1), whose readers drained at their
// iter-(t-1) lgkmcnt(0) before that iter's barrier. Never drains in loop.
// Swizzle (verified conflict-free R1-R4): stored slot s of row r holds chunk
// s ^ ((r>>1)&3); GLL writes linearly so the *source* chunk is permuted:
// kc = (tid&3)^((tid>>3)&3); reads use pos = ((lane>>4)^((lane>>1)&3))*16.
__global__ __launch_bounds__(512, 2) void qlinear_gemm_i8(
    const signed char* __restrict__ Aq,
    const signed char* __restrict__ Bq,
    const float* __restrict__ bias,
    const float* __restrict__ wscale,
    const float* __restrict__ iscale,
    float* __restrict__ C) {
    __shared__ signed char smem[3 * ASLOT];   // 48 KiB, A only

    const int tid  = threadIdx.x;
    const int wave = tid >> 6;
    const int lane = tid & 63;
    const int m0 = blockIdx.x * BM;
    const int n0 = blockIdx.y * BN;
    const int wm = (wave >> 2) * 128;    // {0,128}
    const int wn = (wave & 3) * 64;      // {0,64,128,192}

    int4v acc[8][4];
#pragma unroll
    for (int i = 0; i < 8; ++i)
#pragma unroll
        for (int j = 0; j < 4; ++j)
            acc[i][j] = int4v{0, 0, 0, 0};

    // --- A staging: 512 threads cover one 128-row half (8 KiB) per GLL
    const int kc = ((tid & 3) ^ ((tid >> 3) & 3)) * 16;   // swizzled src chunk
    const signed char* gA  = Aq + (size_t)(m0 + (tid >> 2)) * GK + kc;
    const signed char* gA2 = gA + (size_t)128 * GK;
    const int dst = tid * 16;                             // linear LDS dest

    // --- A fragment read offsets (within one slot)
    const int pos = (((lane >> 4) ^ ((lane >> 1) & 3))) * 16;
    const int fAo = (wm + (lane & 15)) * 64 + pos;        // + mi*1024

    // --- B fragment global pointers (per ni): row = n0+wn+ni*16+(lane&15),
    //     k-chunk = (lane>>4)*16; tile t adds t*64 bytes.
    const signed char* gB0 =
        Bq + (size_t)(n0 + wn + (lane & 15)) * GK + ((lane >> 4) * 16);
    const signed char* gB1 = gB0 + (size_t)16 * GK;
    const signed char* gB2 = gB0 + (size_t)32 * GK;
    const signed char* gB3 = gB0 + (size_t)48 * GK;

#define GLL16(g, l)                                                     \
    __builtin_amdgcn_global_load_lds(                                   \
        (__attribute__((address_space(1))) void*)(void*)(g),            \
        (__attribute__((address_space(3))) void*)(void*)(l), 16, 0, 0)

#define STAGE_A(kb, soff)                                               \
    do {                                                                \
        GLL16(gA  + (kb), smem + (soff) + dst);                         \
        GLL16(gA2 + (kb), smem + (soff) + 8192 + dst);                  \
    } while (0)

#define SB __builtin_amdgcn_sched_barrier(0)
#define MFMA_I8(A, B, Cc) __builtin_amdgcn_mfma_i32_16x16x64_i8(A, B, Cc, 0, 0, 0)

// one K-tile: prefetch B(t+1)->Bn, stage A(t+2), read+compute tile t (B=Bc)
#define SUBITER(Bc0, Bc1, Bc2, Bc3, Bn0, Bn1, Bn2, Bn3)                 \
    do {                                                                \
        Bn0 = *(const int4v*)(gB0 + kbB);                               \
        Bn1 = *(const int4v*)(gB1 + kbB);                               \
        Bn2 = *(const int4v*)(gB2 + kbB);                               \
        Bn3 = *(const int4v*)(gB3 + kbB);                               \
        kbB += BK; if (kbB >= GK) kbB = 0;                              \
        SB;                                                             \
        STAGE_A(kst, sC);                                               \
        kst += BK; if (kst >= GK) kst = 0;                              \
        SB;                                                             \
        {                                                               \
            const signed char* fA = smem + sA + fAo;                    \
            int4v a0 = *(const int4v*)(fA);                             \
            int4v a1 = *(const int4v*)(fA + 1024);                      \
            int4v a2 = *(const int4v*)(fA + 2048);                      \
            int4v a3 = *(const int4v*)(fA + 3072);                      \
            int4v a4 = *(const int4v*)(fA + 4096);                      \
            int4v a5 = *(const int4v*)(fA + 5120);                      \
            int4v a6 = *(const int4v*)(fA + 6144);                      \
            int4v a7 = *(const int4v*)(fA + 7168);                      \
            asm volatile("s_waitcnt vmcnt(8) lgkmcnt(0)" ::: "memory"); \
            SB;                                                         \
            __builtin_amdgcn_s_setprio(1);                              \
            acc[0][0] = MFMA_I8(a0, Bc0, acc[0][0]);                    \
            acc[1][0] = MFMA_I8(a1, Bc0, acc[1][0]);                    \
            acc[2][0] = MFMA_I8(a2, Bc0, acc[2][0]);                    \
            acc[3][0] = MFMA_I8(a3, Bc0, acc[3][0]);                    \
            acc[4][0] = MFMA_I8(a4, Bc0, acc[4][0]);                    \
            acc[5][0] = MFMA_I8(a5, Bc0, acc[5][0]);                    \
            acc[6][0] = MFMA_I8(a6, Bc0, acc[6][0]);                    \
            acc[7][0] = MFMA_I8(a7, Bc0, acc[7][0]);                    \
            acc[0][1] = MFMA_I8(a0, Bc1, acc[0][1]);                    \
            acc[1][1] = MFMA_I8(a1, Bc1, acc[1][1]);                    \
            acc[2][1] = MFMA_I8(a2, Bc1, acc[2][1]);                    \
            acc[3][1] = MFMA_I8(a3, Bc1, acc[3][1]);                    \
            acc[4][1] = MFMA_I8(a4, Bc1, acc[4][1]);                    \
            acc[5][1] = MFMA_I8(a5, Bc1, acc[5][1]);                    \
            acc[6][1] = MFMA_I8(a6, Bc1, acc[6][1]);                    \
            acc[7][1] = MFMA_I8(a7, Bc1, acc[7][1]);                    \
            acc[0][2] = MFMA_I8(a0, Bc2, acc[0][2]);                    \
            acc[1][2] = MFMA_I8(a1, Bc2, acc[1][2]);                    \
            acc[2][2] = MFMA_I8(a2, Bc2, acc[2][2]);                    \
            acc[3][2] = MFMA_I8(a3, Bc2, acc[3][2]);                    \
            acc[4][2] = MFMA_I8(a4, Bc2, acc[4][2]);                    \
            acc[5][2] = MFMA_I8(a5, Bc2, acc[5][2]);                    \
            acc[6][2] = MFMA_I8(a6, Bc2, acc[6][2]);                    \
            acc[7][2] = MFMA_I8(a7, Bc2, acc[7][2]);                    \
            acc[0][3] = MFMA_I8(a0, Bc3, acc[0][3]);                    \
            acc[1][3] = MFMA_I8(a1, Bc3, acc[1][3]);                    \
            acc[2][3] = MFMA_I8(a2, Bc3, acc[2][3]);                    \
            acc[3][3] = MFMA_I8(a3, Bc3, acc[3][3]);                    \
            acc[4][3] = MFMA_I8(a4, Bc3, acc[4][3]);                    \
            acc[5][3] = MFMA_I8(a5, Bc3, acc[5][3]);                    \
            acc[6][3] = MFMA_I8(a6, Bc3, acc[6][3]);                    \
            acc[7][3] = MFMA_I8(a7, Bc3, acc[7][3]);                    \
            __builtin_amdgcn_s_setprio(0);                              \
        }                                                               \
        asm volatile("s_waitcnt vmcnt(6)" ::: "memory");                \
        __builtin_amdgcn_s_barrier();                                   \
        SB;                                                             \
        { int t_ = sA; sA = sB_; sB_ = sC; sC = t_; }                   \
    } while (0)

    // --- prologue.  VMEM order: GLL A(0) x2, B(0) x4, GLL A(1) x2.
    // vmcnt(6) retires GLL A(0); leaves [B(0) 4, GLL A(1) 2] = invariant.
    STAGE_A(0, 0);
    SB;
    int4v bX0 = *(const int4v*)(gB0);
    int4v bX1 = *(const int4v*)(gB1);
    int4v bX2 = *(const int4v*)(gB2);
    int4v bX3 = *(const int4v*)(gB3);
    SB;
    STAGE_A(BK, ASLOT);
    SB;
    asm volatile("s_waitcnt vmcnt(6)" ::: "memory");
    __builtin_amdgcn_s_barrier();
    SB;

    int4v bY0, bY1, bY2, bY3;
    int sA = 0, sB_ = ASLOT, sC = 2 * ASLOT;   // slots of tiles t, t+1, t+2
    int kbB = BK;        // k-byte of B(t+1) prefetch
    int kst = 2 * BK;    // k-byte of A(t+2) staging (wraps: harmless re-read)
    for (int it = 0; it < NTILE / 2; ++it) {
        SUBITER(bX0, bX1, bX2, bX3, bY0, bY1, bY2, bY3);   // even tile
        SUBITER(bY0, bY1, bY2, bY3, bX0, bX1, bX2, bX3);   // odd tile
    }

    // --- epilogue: C/D layout col=lane&15, row=(lane>>4)*4+reg
    const float isc = *iscale;
#pragma unroll
    for (int ni = 0; ni < 4; ++ni) {
        const int col = n0 + wn + ni * 16 + (lane & 15);
        const float bs_ = bias[col];
        const float inv = 1.0f / (wscale[col] * isc);
#pragma unroll
        for (int mi = 0; mi < 8; ++mi) {
            const int row0 = m0 + wm + mi * 16 + (lane >> 4) * 4;
#pragma unroll
            for (int r = 0; r < 4; ++r) {
                C[(size_t)(row0 + r) * GN + col] =
                    ((float)acc[mi][ni][r] + bs_) * inv;
            }
        }
    }
#undef SUBITER
#undef MFMA_I8
#undef SB
#undef STAGE_A
#undef GLL16
}

extern "C" void kernel_launch(void* const* d_in, const int* in_sizes, int n_in,
                              void* d_out, int out_size, void* d_ws, size_t ws_size,
                              hipStream_t stream) {
    const float* x      = (const float*)d_in[0];  // (4,2048,4096)
    const float* w      = (const float*)d_in[1];  // (4096,4096)
    const float* bias   = (const float*)d_in[2];  // (4096,)
    const float* wscale = (const float*)d_in[3];  // (4096,)
    const float* iscale = (const float*)d_in[4];  // (1,)
    float* out = (float*)d_out;

    signed char* xq = (signed char*)d_ws;                       // 32 MiB
    signed char* wq = xq + (size_t)GM * GK;                     // 16 MiB

    const int n4x = GM * GK / 4;
    const int n4w = GN * GK / 4;
    quant_xw_k<<<3072, 256, 0, stream>>>((const float4*)x, (unsigned int*)xq,
                                         (const float4*)w, (unsigned int*)wq,
                                         wscale, iscale, n4x, n4x + n4w);

    dim3 grid(GM / BM, GN / BN);   // 32 x 16 = 512 blocks of 512 threads
    qlinear_gemm_i8<<<grid, 512, 0, stream>>>(xq, wq, bias, wscale, iscale, out);
}